// Round 12
// baseline (611.843 us; speedup 1.0000x reference)
//
#include <hip/hip_runtime.h>
#include <hip/hip_bf16.h>

// EvenOddFunctionHAM: out = rho(rho(s)@W + b_odd + [Ux|0]) @ W^T + b_even
// R11 -> R12: producer/consumer split-K balance. Light block (32 K-tiles)
// also computes K[0,1024) of its heavy partner -> f32 partial in d_out
// (free region) + flag release. Heavy block computes K[1024,4096) (48
// tiles), acquires flag, adds partial, epilogues. Both roles = 48 tiles:
// critical path 64 -> 48. Grid 256 = 1 block/CU (160KB LDS) => all
// co-resident; producers are ids 0..127 (dispatched first). Deterministic:
// fixed add order, flags memset per call. Tile loop = R11 unchanged.

#define N_DIM 4096
#define D1_DIM 2048

typedef short short8 __attribute__((ext_vector_type(8)));
typedef float f32x4 __attribute__((ext_vector_type(4)));

__device__ __forceinline__ float rho_f(float x) {
    return 1.0f / (1.0f + __expf(2.0f - 4.0f * x));  // sigmoid(4x-2)
}

__device__ __forceinline__ unsigned short f2bf(float x) {
    unsigned int u = __builtin_bit_cast(unsigned int, x);
    u += 0x7fffu + ((u >> 16) & 1u);
    return (unsigned short)(u >> 16);
}

__device__ __forceinline__ void gl_lds16(const unsigned short* g, void* l) {
    __builtin_amdgcn_global_load_lds(
        (const __attribute__((address_space(1))) void*)g,
        (__attribute__((address_space(3))) void*)l, 16, 0, 0);
}

// ---------------- merged prep (unchanged from R8) ----------------
__global__ __launch_bounds__(256) void prep_kernel(
    const float* __restrict__ s, const float* __restrict__ W,
    unsigned short* __restrict__ Rs, unsigned short* __restrict__ Wb,
    unsigned short* __restrict__ WTb) {
    __shared__ unsigned short t[32][33];
    const int id = blockIdx.x;
    if (id < 16384) {
        const int bx = id & 127, by = id >> 7;
        if (by * 32 >= D1_DIM && bx * 32 < D1_DIM) return;  // dead block
        const int tx = threadIdx.x & 31, ty = threadIdx.x >> 5;  // 32 x 8
        const int x = bx * 32 + tx;
        #pragma unroll
        for (int r = 0; r < 4; r++) {
            const int y = by * 32 + ty + r * 8;
            const size_t idx = (size_t)y * N_DIM + x;
            const unsigned short b = f2bf(W[idx]);
            Wb[idx] = b;
            t[ty + r * 8][tx] = b;
        }
        __syncthreads();
        #pragma unroll
        for (int r = 0; r < 4; r++) {
            const int yy = ty + r * 8;
            WTb[(size_t)(bx * 32 + yy) * N_DIM + (by * 32 + tx)] = t[tx][yy];
        }
    } else {
        const int n8 = (N_DIM * N_DIM) / 8;
        const int stride = 2048 * 256;
        for (int i = (id - 16384) * 256 + threadIdx.x; i < n8; i += stride) {
            float4 a = ((const float4*)s)[2 * i];
            float4 b = ((const float4*)s)[2 * i + 1];
            unsigned int r0 = f2bf(rho_f(a.x)) | ((unsigned int)f2bf(rho_f(a.y)) << 16);
            unsigned int r1 = f2bf(rho_f(a.z)) | ((unsigned int)f2bf(rho_f(a.w)) << 16);
            unsigned int r2 = f2bf(rho_f(b.x)) | ((unsigned int)f2bf(rho_f(b.y)) << 16);
            unsigned int r3 = f2bf(rho_f(b.z)) | ((unsigned int)f2bf(rho_f(b.w)) << 16);
            uint4 o; o.x = r0; o.y = r1; o.z = r2; o.w = r3;
            ((uint4*)Rs)[i] = o;
        }
    }
}

// ---------------- GEMM 256x256, BK=64, 16 waves, R11 tile loop ----------
template<int MODE>
__global__ __launch_bounds__(1024, 4) void gemm_kernel(
    const unsigned short* __restrict__ A,
    const unsigned short* __restrict__ Bt,
    void* __restrict__ Out,
    const float* __restrict__ Ux,
    const float* __restrict__ bias,
    float* __restrict__ pbuf,
    unsigned int* __restrict__ flags,
    const int split) {
    __shared__ __align__(16) char lds[163840];

    const int id = blockIdx.x;
    const int tid = threadIdx.x;
    const int w = tid >> 6;
    const int L = tid & 63;
    const int wr = w >> 2;
    const int wc = w & 3;
    const int fr = L & 15;
    const int fq = L >> 4;
    const int swz = fr & 7;

    const int srl = w * 8 + (L >> 3);
    const int schunk8 = ((L & 7) ^ (L >> 3)) << 3;
    const int wbase = w * 1024;

    // role & geometry
    int brow, bcol;          // this block's output tile
    int kbeg, nk;            // own compute K range (in 64-wide tiles)
    int role = 0;            // 0 = plain (no split), 1 = producer, 2 = consumer
    int bcolH = 0, pidx = 0; // partner heavy col / partial index
    if (split) {
        const int i = id & 127;
        const int by = i >> 3, bg = i & 7;
        brow = by << 8;
        pidx = i;
        if (id < 128) {      // producer (light)
            role = 1;
            if (MODE == 1) { bcol = bg << 8;          kbeg = 0;    bcolH = D1_DIM + (bg << 8); }
            else           { bcol = D1_DIM + (bg << 8); kbeg = 2048; bcolH = bg << 8; }
            nk = 32;
        } else {             // consumer (heavy)
            role = 2;
            bcol = (MODE == 1) ? (D1_DIM + (bg << 8)) : (bg << 8);
            kbeg = 1024; nk = 48;
        }
    } else {
        const int wg = ((id & 7) << 5) | (id >> 3);
        brow = (wg >> 4) << 8; bcol = (wg & 15) << 8;
        if (MODE == 1) { kbeg = 0; nk = (bcol < D1_DIM) ? 32 : 64; }
        else           { kbeg = (bcol < D1_DIM) ? 0 : D1_DIM; nk = (bcol < D1_DIM) ? 64 : 32;
                         if (bcol < D1_DIM) kbeg = 0; else kbeg = D1_DIM; }
    }

    f32x4 acc[4][4];
    short8 af[2][4], bf[4];

#define STAGEF(rowbase, kcol, base) do {                                       \
        const unsigned short* g0_ = (rowbase) + (kcol);                        \
        gl_lds16(g0_, lds + (base) + wbase);                                   \
        gl_lds16(g0_ + 128 * N_DIM, lds + (base) + 16384 + wbase);             \
    } while (0)
#define LDA_K(ab, ks) do {                                                     \
        _Pragma("unroll") for (int m_ = 0; m_ < 4; ++m_) {                     \
            const int R_ = wr * 64 + m_ * 16 + fr;                             \
            af[ks][m_] = *(const short8*)(lds + (ab) + R_ * 128 +              \
                ((((ks) * 4 + fq) ^ swz) << 4)); }                             \
    } while (0)
#define LDB_K(bb, ks) do {                                                     \
        _Pragma("unroll") for (int n_ = 0; n_ < 4; ++n_) {                     \
            const int R_ = wc * 64 + n_ * 16 + fr;                             \
            bf[n_] = *(const short8*)(lds + (bb) + R_ * 128 +                  \
                ((((ks) * 4 + fq) ^ swz) << 4)); }                             \
    } while (0)
#define MFMA_K(ks) do {                                                        \
        __builtin_amdgcn_s_setprio(1);                                         \
        _Pragma("unroll") for (int m_ = 0; m_ < 4; ++m_)                       \
        _Pragma("unroll") for (int n_ = 0; n_ < 4; ++n_)                       \
            acc[m_][n_] = __builtin_amdgcn_mfma_f32_16x16x32_bf16(             \
                af[ks][m_], bf[n_], acc[m_][n_], 0, 0, 0);                     \
        __builtin_amdgcn_s_setprio(0);                                         \
    } while (0)
#define SBAR0() __builtin_amdgcn_sched_barrier(0)
#define LGKM(n) do { asm volatile("s_waitcnt lgkmcnt(" #n ")" ::: "memory");   \
                     SBAR0(); } while (0)
#define BAR() __builtin_amdgcn_s_barrier()

    // R11 tile loop over [kb, kb + n*64), B panel rows at column-tile bc.
    auto run_tiles = [&](int bc, int kb, int n) {
        #pragma unroll
        for (int i2 = 0; i2 < 4; i2++)
            #pragma unroll
            for (int j2 = 0; j2 < 4; j2++)
                acc[i2][j2] = (f32x4){0.f, 0.f, 0.f, 0.f};
        const unsigned short* Arow = A + (size_t)(brow + srl) * N_DIM + schunk8 + kb;
        const unsigned short* Brow = Bt + (size_t)(bc + srl) * N_DIM + schunk8 + kb;
        // prologue: A(0),B(0),A(1),B(1) FIFO; vmcnt(4): t0 ready
        STAGEF(Arow, 0, 0);      STAGEF(Brow, 0, 98304);
        STAGEF(Arow, 64, 32768); STAGEF(Brow, 64, 131072);
        asm volatile("s_waitcnt vmcnt(4)" ::: "memory");
        BAR();
        int ai = 0, si = 2;
        for (int t = 0; t < n; ++t) {
            const int aB = ai * 32768;
            const int sA = si * 32768;
            const int bB = 98304 + (t & 1) * 32768;
            const int t2 = (t + 2 < n) ? (t + 2) : (n - 1);  // clamp tail
            const int ka = t2 << 6;
            STAGEF(Arow, ka, sA);
            LDA_K(aB, 0); SBAR0();
            LDB_K(bB, 0); SBAR0();
            LDA_K(aB, 1); SBAR0();
            LGKM(4);
            MFMA_K(0);
            LDB_K(bB, 1); SBAR0();
            LGKM(0);
            MFMA_K(1);
            asm volatile("s_waitcnt vmcnt(2)" ::: "memory");
            BAR();
            STAGEF(Brow, ka, bB);
            ai++; if (ai == 3) ai = 0;
            si++; if (si == 3) si = 0;
        }
        asm volatile("s_waitcnt vmcnt(0)" ::: "memory");
        BAR();   // LDS quiescent before any next phase re-stages
    };

    if (role == 1) {
        // ---- producer: own block, epilogue; then partner partial ----
        run_tiles(bcol, kbeg, nk);
        const bool hasUx = (MODE == 1);   // light MODE1 cols < 2048
        #pragma unroll
        for (int m = 0; m < 4; m++) {
            const int row0 = brow + wr * 64 + m * 16 + fq * 4;
            #pragma unroll
            for (int n = 0; n < 4; n++) {
                const int col = bcol + wc * 64 + n * 16 + fr;
                const float bv = bias[col];
                #pragma unroll
                for (int r = 0; r < 4; r++) {
                    const int row = row0 + r;
                    float v = acc[m][n][r] + bv;
                    if (MODE == 1) {
                        if (hasUx) v += Ux[(size_t)row * D1_DIM + col];
                        ((unsigned short*)Out)[(size_t)row * N_DIM + col] = f2bf(rho_f(v));
                    } else {
                        ((float*)Out)[(size_t)row * N_DIM + col] = v;
                    }
                }
            }
        }
        // partial: K[0,1024) of partner heavy tile -> pbuf (raw f32)
        run_tiles(bcolH, 0, 16);
        #pragma unroll
        for (int m = 0; m < 4; m++) {
            const int row0 = brow + wr * 64 + m * 16 + fq * 4;
            #pragma unroll
            for (int n = 0; n < 4; n++) {
                const int col = bcolH + wc * 64 + n * 16 + fr;
                #pragma unroll
                for (int r = 0; r < 4; r++)
                    pbuf[(size_t)(row0 + r) * N_DIM + col] = acc[m][n][r];
            }
        }
        __syncthreads();
        if (tid == 0) {
            __threadfence();   // flush partial to device-visible point
            __hip_atomic_store(&flags[pidx], 1u, __ATOMIC_RELEASE,
                               __HIP_MEMORY_SCOPE_AGENT);
        }
    } else {
        // ---- consumer (role 2) or plain (role 0) ----
        run_tiles(bcol, kbeg, nk);
        if (role == 2) {
            if (tid == 0) {
                while (__hip_atomic_load(&flags[pidx], __ATOMIC_ACQUIRE,
                                         __HIP_MEMORY_SCOPE_AGENT) == 0u)
                    __builtin_amdgcn_s_sleep(2);
                __threadfence();   // acquire: invalidate stale cached lines
            }
            __syncthreads();
        }
        const bool hasUx = (!split) && (MODE == 1) && (bcol < D1_DIM);
        #pragma unroll
        for (int m = 0; m < 4; m++) {
            const int row0 = brow + wr * 64 + m * 16 + fq * 4;
            #pragma unroll
            for (int n = 0; n < 4; n++) {
                const int col = bcol + wc * 64 + n * 16 + fr;
                const float bv = bias[col];
                #pragma unroll
                for (int r = 0; r < 4; r++) {
                    const int row = row0 + r;
                    float v = acc[m][n][r] + bv;
                    if (role == 2)   // add partner's partial (agent-scope load)
                        v += __hip_atomic_load(&pbuf[(size_t)row * N_DIM + col],
                                               __ATOMIC_RELAXED,
                                               __HIP_MEMORY_SCOPE_AGENT);
                    if (MODE == 1) {
                        if (hasUx) v += Ux[(size_t)row * D1_DIM + col];
                        ((unsigned short*)Out)[(size_t)row * N_DIM + col] = f2bf(rho_f(v));
                    } else {
                        ((float*)Out)[(size_t)row * N_DIM + col] = v;
                    }
                }
            }
        }
    }
#undef STAGEF
#undef LDA_K
#undef LDB_K
#undef MFMA_K
#undef SBAR0
#undef LGKM
#undef BAR
}

extern "C" void kernel_launch(void* const* d_in, const int* in_sizes, int n_in,
                              void* d_out, int out_size, void* d_ws, size_t ws_size,
                              hipStream_t stream) {
    const float* Ux     = (const float*)d_in[0];  // [4096][2048]
    const float* s      = (const float*)d_in[1];  // [4096][4096]
    const float* W      = (const float*)d_in[2];  // [4096][4096]
    const float* b_even = (const float*)d_in[3];  // [4096]
    const float* b_odd  = (const float*)d_in[4];  // [4096]
    // d_in[5] = W_mask: unused (masked block is never read)

    char* ws = (char*)d_ws;
    const size_t SZ = (size_t)N_DIM * N_DIM * 2;  // 32 MB per bf16 matrix
    unsigned short* Rs  = (unsigned short*)(ws);
    unsigned short* R2  = (unsigned short*)(ws + SZ);
    unsigned short* Wb  = (unsigned short*)(ws + 2 * SZ);
    unsigned short* WTb = (unsigned short*)(ws + 3 * SZ);

    const int split = (ws_size >= 4 * SZ + 4096) ? 1 : 0;
    unsigned int* flags = (unsigned int*)(ws + 4 * SZ);
    float* pbuf = (float*)d_out;   // free during GEMM1; GEMM2 partial =
                                   // its own output slot (read-then-write)
    if (split)
        hipMemsetAsync(flags, 0, 1024, stream);

    prep_kernel<<<18432, 256, 0, stream>>>(s, W, Rs, Wb, WTb);
    // GEMM1: s_odd = Rs @ W  (+b_odd, +Ux, rho) -> R2 bf16
    gemm_kernel<1><<<256, 1024, 0, stream>>>(Rs, WTb, (void*)R2, Ux, b_odd,
                                             pbuf, flags, split);
    // GEMM2: out = R2 @ W^T (+b_even) -> d_out f32
    gemm_kernel<2><<<256, 1024, 0, stream>>>(R2, Wb, d_out, Ux, b_even,
                                             pbuf, flags + 128, split);
}

// Round 13
// 238.159 us; speedup vs baseline: 2.5691x; 2.5691x over previous
//
#include <hip/hip_runtime.h>
#include <hip/hip_bf16.h>

// EvenOddFunctionHAM: out = rho(rho(s)@W + b_odd + [Ux|0]) @ W^T + b_even
// R12 -> R13: pure revert to R11 (best verified, 242.0us wall). Split-K
// producer/consumer (R12) serialized (consumers spin while producers run a
// second full pass; FETCH +91%) — dynamic cross-block balancing is dead on
// this dependency chain. R11 = 256x256/BK=64/16-wave/4 waves/SIMD, 3xA+2xB
// LDS bufs, chunk-XOR swizzle, 1 barrier/K-tile, counted vmcnt(2).

#define N_DIM 4096
#define D1_DIM 2048

typedef short short8 __attribute__((ext_vector_type(8)));
typedef float f32x4 __attribute__((ext_vector_type(4)));

__device__ __forceinline__ float rho_f(float x) {
    return 1.0f / (1.0f + __expf(2.0f - 4.0f * x));  // sigmoid(4x-2)
}

__device__ __forceinline__ unsigned short f2bf(float x) {
    unsigned int u = __builtin_bit_cast(unsigned int, x);
    u += 0x7fffu + ((u >> 16) & 1u);
    return (unsigned short)(u >> 16);
}

__device__ __forceinline__ void gl_lds16(const unsigned short* g, void* l) {
    __builtin_amdgcn_global_load_lds(
        (const __attribute__((address_space(1))) void*)g,
        (__attribute__((address_space(3))) void*)l, 16, 0, 0);
}

// ---------------- merged prep (unchanged from R8) ----------------
__global__ __launch_bounds__(256) void prep_kernel(
    const float* __restrict__ s, const float* __restrict__ W,
    unsigned short* __restrict__ Rs, unsigned short* __restrict__ Wb,
    unsigned short* __restrict__ WTb) {
    __shared__ unsigned short t[32][33];
    const int id = blockIdx.x;
    if (id < 16384) {
        const int bx = id & 127, by = id >> 7;
        if (by * 32 >= D1_DIM && bx * 32 < D1_DIM) return;  // dead block
        const int tx = threadIdx.x & 31, ty = threadIdx.x >> 5;  // 32 x 8
        const int x = bx * 32 + tx;
        #pragma unroll
        for (int r = 0; r < 4; r++) {
            const int y = by * 32 + ty + r * 8;
            const size_t idx = (size_t)y * N_DIM + x;
            const unsigned short b = f2bf(W[idx]);
            Wb[idx] = b;
            t[ty + r * 8][tx] = b;
        }
        __syncthreads();
        #pragma unroll
        for (int r = 0; r < 4; r++) {
            const int yy = ty + r * 8;
            WTb[(size_t)(bx * 32 + yy) * N_DIM + (by * 32 + tx)] = t[tx][yy];
        }
    } else {
        const int n8 = (N_DIM * N_DIM) / 8;
        const int stride = 2048 * 256;
        for (int i = (id - 16384) * 256 + threadIdx.x; i < n8; i += stride) {
            float4 a = ((const float4*)s)[2 * i];
            float4 b = ((const float4*)s)[2 * i + 1];
            unsigned int r0 = f2bf(rho_f(a.x)) | ((unsigned int)f2bf(rho_f(a.y)) << 16);
            unsigned int r1 = f2bf(rho_f(a.z)) | ((unsigned int)f2bf(rho_f(a.w)) << 16);
            unsigned int r2 = f2bf(rho_f(b.x)) | ((unsigned int)f2bf(rho_f(b.y)) << 16);
            unsigned int r3 = f2bf(rho_f(b.z)) | ((unsigned int)f2bf(rho_f(b.w)) << 16);
            uint4 o; o.x = r0; o.y = r1; o.z = r2; o.w = r3;
            ((uint4*)Rs)[i] = o;
        }
    }
}

// ---------------- GEMM 256x256, BK=64, 16 waves (4x4), 1 barrier/tile ----
// C = A @ Bt^T. A[M][K], Bt[N][K] bf16 row-major (ld=4096), fp32 acc.
// LDS: A bufs 0/32K/64K (tile t reads a[t%3]; A(t+2)->a[(t+2)%3] at tile
// top); B bufs 96K/128K (tile t reads b[t%2]; B(t+2)->b[t%2] AFTER the
// tile barrier — readers of that slot are past it). vmcnt(2) before BAR
// drains exactly tile t+1's A+B (FIFO), leaves A(t+2) in flight.
// Swizzle: LDS[r][chunk c] = G[r][c ^ (r&7)], source-side + read-side.
template<int MODE>
__global__ __launch_bounds__(1024, 4) void gemm_kernel(
    const unsigned short* __restrict__ A,
    const unsigned short* __restrict__ Bt,
    void* __restrict__ Out,
    const float* __restrict__ Ux,
    const float* __restrict__ bias) {
    __shared__ __align__(16) char lds[163840];

    // XCD remap: XCD x gets tile-rows {2x, 2x+1}
    const int id = blockIdx.x;
    const int wg = ((id & 7) << 5) | (id >> 3);
    const int by = wg >> 4, bx = wg & 15;
    const int brow = by << 8, bcol = bx << 8;

    const int tid = threadIdx.x;
    const int w = tid >> 6;        // wave 0..15
    const int L = tid & 63;
    const int wr = w >> 2;         // 0..3 : rows wr*64..+63
    const int wc = w & 3;          // 0..3 : cols wc*64..+63
    const int fr = L & 15;
    const int fq = L >> 4;
    const int swz = fr & 7;

    // block-sparse K range (exact: skipped W blocks are all-zero)
    int kbeg, kend;
    if (MODE == 1) { kbeg = 0; kend = (bcol < D1_DIM) ? D1_DIM : N_DIM; }
    else           { kbeg = (bcol < D1_DIM) ? 0 : D1_DIM; kend = N_DIM; }

    // staging: one gl_lds16/thread = 128 rows x 64 cols (16KB); full 256-row
    // matrix tile = 2 instrs. wave w covers rows w*8+(L>>3) (+128 for h=1).
    const int srl = w * 8 + (L >> 3);
    const int schunk8 = ((L & 7) ^ (L >> 3)) << 3;
    const int wbase = w * 1024;
#define STAGEF(mat, gb, kcol, base) do {                                       \
        const unsigned short* g0_ = (mat) +                                    \
            (size_t)((gb) + srl) * N_DIM + (kcol) + schunk8;                   \
        gl_lds16(g0_, lds + (base) + wbase);                                   \
        gl_lds16(g0_ + 128 * N_DIM, lds + (base) + 16384 + wbase);             \
    } while (0)

    short8 af[2][4], bf[4];
#define LDA_K(ab, ks) do {                                                     \
        _Pragma("unroll") for (int m_ = 0; m_ < 4; ++m_) {                     \
            const int R_ = wr * 64 + m_ * 16 + fr;                             \
            af[ks][m_] = *(const short8*)(lds + (ab) + R_ * 128 +              \
                ((((ks) * 4 + fq) ^ swz) << 4)); }                             \
    } while (0)
#define LDB_K(bb, ks) do {                                                     \
        _Pragma("unroll") for (int n_ = 0; n_ < 4; ++n_) {                     \
            const int R_ = wc * 64 + n_ * 16 + fr;                             \
            bf[n_] = *(const short8*)(lds + (bb) + R_ * 128 +                  \
                ((((ks) * 4 + fq) ^ swz) << 4)); }                             \
    } while (0)

    f32x4 acc[4][4];
    #pragma unroll
    for (int i = 0; i < 4; i++)
        #pragma unroll
        for (int j = 0; j < 4; j++)
            acc[i][j] = (f32x4){0.f, 0.f, 0.f, 0.f};

#define MFMA_K(ks) do {                                                        \
        __builtin_amdgcn_s_setprio(1);                                         \
        _Pragma("unroll") for (int m_ = 0; m_ < 4; ++m_)                       \
        _Pragma("unroll") for (int n_ = 0; n_ < 4; ++n_)                       \
            acc[m_][n_] = __builtin_amdgcn_mfma_f32_16x16x32_bf16(             \
                af[ks][m_], bf[n_], acc[m_][n_], 0, 0, 0);                     \
        __builtin_amdgcn_s_setprio(0);                                         \
    } while (0)

#define SBAR0() __builtin_amdgcn_sched_barrier(0)
#define LGKM(n) do { asm volatile("s_waitcnt lgkmcnt(" #n ")" ::: "memory");   \
                     SBAR0(); } while (0)
#define BAR() __builtin_amdgcn_s_barrier()

    const int nk = (kend - kbeg) >> 6;   // 32 or 64
    const int km = nk - 1;

    // ---- prologue: A(0),B(0),A(1),B(1) (8 loads FIFO); vmcnt(4): t0 ready
    {
        const int k0 = kbeg;
        const int k1 = kbeg + ((1 & km) << 6);
        STAGEF(A, brow, k0, 0);       STAGEF(Bt, bcol, k0, 98304);
        STAGEF(A, brow, k1, 32768);   STAGEF(Bt, bcol, k1, 131072);
        asm volatile("s_waitcnt vmcnt(4)" ::: "memory");
        BAR();
    }

    int ai = 0, si = 2;                   // a[t%3], a[(t+2)%3]
    for (int t = 0; t < nk; ++t) {
        const int aB = ai * 32768;
        const int sA = si * 32768;
        const int bB = 98304 + (t & 1) * 32768;
        const int ka = kbeg + (((t + 2) & km) << 6);   // wrapped tail: dead

        // top: stage A(t+2) -> a[(t+2)%3] (slot read at t-1, post-barrier)
        STAGEF(A, brow, ka, sA);
        // reads: A0(4), B0(4), A1(4) up-front
        LDA_K(aB, 0); SBAR0();
        LDB_K(bB, 0); SBAR0();
        LDA_K(aB, 1); SBAR0();
        LGKM(4);                       // A0+B0 landed (A1 may be in flight)
        MFMA_K(0);
        LDB_K(bB, 1); SBAR0();         // re-read bf for ks1 (WAR-safe)
        LGKM(0);                       // +A1,B1 landed
        MFMA_K(1);
        // drain exactly tile t+1's 4 loads (FIFO: A(t+1),B(t+1) oldest),
        // keep A(t+2)'s 2 in flight
        asm volatile("s_waitcnt vmcnt(2)" ::: "memory");
        BAR();                         // single tile barrier
        // bottom: stage B(t+2) -> b[t%2] (readers of this slot passed BAR)
        STAGEF(Bt, bcol, ka, bB);
        ai++; if (ai == 3) ai = 0;
        si++; if (si == 3) si = 0;
    }
    // drain dead tail stages: must not land in the NEXT block's LDS
    asm volatile("s_waitcnt vmcnt(0)" ::: "memory");

    // ---- epilogue: C/D layout col = fr (N), row = fq*4 + reg (M) ----
    const bool hasUx = (MODE == 1) && (bcol < D1_DIM);
    #pragma unroll
    for (int m = 0; m < 4; m++) {
        const int row0 = brow + wr * 64 + m * 16 + fq * 4;
        #pragma unroll
        for (int n = 0; n < 4; n++) {
            const int col = bcol + wc * 64 + n * 16 + fr;
            const float bv = bias[col];
            #pragma unroll
            for (int r = 0; r < 4; r++) {
                const int row = row0 + r;
                float v = acc[m][n][r] + bv;
                if (MODE == 1) {
                    if (hasUx) v += Ux[(size_t)row * D1_DIM + col];
                    ((unsigned short*)Out)[(size_t)row * N_DIM + col] =
                        f2bf(rho_f(v));
                } else {
                    ((float*)Out)[(size_t)row * N_DIM + col] = v;
                }
            }
        }
    }
#undef STAGEF
#undef LDA_K
#undef LDB_K
#undef MFMA_K
#undef SBAR0
#undef LGKM
#undef BAR
}

extern "C" void kernel_launch(void* const* d_in, const int* in_sizes, int n_in,
                              void* d_out, int out_size, void* d_ws, size_t ws_size,
                              hipStream_t stream) {
    const float* Ux     = (const float*)d_in[0];  // [4096][2048]
    const float* s      = (const float*)d_in[1];  // [4096][4096]
    const float* W      = (const float*)d_in[2];  // [4096][4096]
    const float* b_even = (const float*)d_in[3];  // [4096]
    const float* b_odd  = (const float*)d_in[4];  // [4096]
    // d_in[5] = W_mask: unused (masked block is never read)

    char* ws = (char*)d_ws;
    const size_t SZ = (size_t)N_DIM * N_DIM * 2;  // 32 MB per bf16 matrix
    unsigned short* Rs  = (unsigned short*)(ws);
    unsigned short* R2  = (unsigned short*)(ws + SZ);
    unsigned short* Wb  = (unsigned short*)(ws + 2 * SZ);
    unsigned short* WTb = (unsigned short*)(ws + 3 * SZ);

    // merged prep: 16384 W-tile blocks + 2048 rho(s) blocks
    prep_kernel<<<18432, 256, 0, stream>>>(s, W, Rs, Wb, WTb);
    // GEMM1: s_odd = Rs @ W  (+b_odd, +Ux, rho) -> R2 bf16
    gemm_kernel<1><<<256, 1024, 0, stream>>>(Rs, WTb, (void*)R2, Ux, b_odd);
    // GEMM2: out = R2 @ W^T (+b_even) -> d_out f32
    gemm_kernel<2><<<256, 1024, 0, stream>>>(R2, Wb, d_out, Ux, b_even);
}